// Round 1
// baseline (1253.283 us; speedup 1.0000x reference)
//
#include <hip/hip_runtime.h>
#include <hip/hip_bf16.h>
#include <cstdint>

#define CAP 64

__device__ __forceinline__ float lrelu(float v) { return fmaxf(v, 0.2f * v); }

// ---------------- CSR bucket build: one int atomic per edge ----------------
__global__ __launch_bounds__(256) void k_build(const int* __restrict__ ei, int E,
                                               int* __restrict__ cnt, int* __restrict__ bucket) {
    int e = blockIdx.x * 256 + threadIdx.x;
    if (e >= E) return;
    int s = ei[e];
    int d = ei[E + e];
    int slot = atomicAdd(&cnt[d], 1);
    if (slot < CAP) bucket[(size_t)d * CAP + slot] = s;
}

// ---------------- GEMM1: h1[N,64] = x[N,128] @ W1[128,64] ----------------
// 64-row tile in LDS (padded stride 132 -> conflict-free b128 reads), W1 read
// from global (32KB, L1-resident). 4x4 register block per thread.
__global__ __launch_bounds__(256) void k_gemm1(const float* __restrict__ x,
                                               const float* __restrict__ W,
                                               float* __restrict__ h1, int N) {
    __shared__ float xs[64 * 132];
    const int t = threadIdx.x;
    const int rowBase = blockIdx.x * 64;
#pragma unroll
    for (int i = 0; i < 8; ++i) {
        int g = i * 256 + t;              // [0,2048) float4s
        int r = g >> 5, c4 = (g & 31) << 2;
        float4 v = make_float4(0.f, 0.f, 0.f, 0.f);
        int row = rowBase + r;
        if (row < N) v = *(const float4*)(x + (size_t)row * 128 + c4);
        *(float4*)(&xs[r * 132 + c4]) = v;
    }
    __syncthreads();
    const int tx = t & 15;   // cols 4tx..4tx+3
    const int ty = t >> 4;   // rows 4ty..4ty+3
    float acc[4][4] = {};
#pragma unroll
    for (int kc = 0; kc < 32; ++kc) {
        float4 a[4];
#pragma unroll
        for (int i = 0; i < 4; ++i) a[i] = *(const float4*)(&xs[(4 * ty + i) * 132 + kc * 4]);
        float4 w[4];
#pragma unroll
        for (int kk = 0; kk < 4; ++kk) w[kk] = *(const float4*)(W + (size_t)(kc * 4 + kk) * 64 + tx * 4);
#pragma unroll
        for (int i = 0; i < 4; ++i) {
            const float* ai = (const float*)&a[i];
#pragma unroll
            for (int j = 0; j < 4; ++j) {
                acc[i][j] += ai[0] * ((const float*)&w[0])[j]
                           + ai[1] * ((const float*)&w[1])[j]
                           + ai[2] * ((const float*)&w[2])[j]
                           + ai[3] * ((const float*)&w[3])[j];
            }
        }
    }
#pragma unroll
    for (int i = 0; i < 4; ++i) {
        int row = rowBase + 4 * ty + i;
        if (row < N) {
            float4 o = make_float4(acc[i][0], acc[i][1], acc[i][2], acc[i][3]);
            *(float4*)(h1 + (size_t)row * 64 + tx * 4) = o;
        }
    }
}

// ---------------- GEMM2: h2[N,80] = helu[N,64] @ W2[64,80] ----------------
__global__ __launch_bounds__(256) void k_gemm2(const float* __restrict__ hin,
                                               const float* __restrict__ W,
                                               float* __restrict__ h2, int N) {
    __shared__ float xs[64 * 68];   // 17,408 B
    __shared__ float wt[80 * 68];   // 21,760 B (W2 transposed)
    const int t = threadIdx.x;
    const int rowBase = blockIdx.x * 64;
#pragma unroll
    for (int i = 0; i < 4; ++i) {
        int g = i * 256 + t;              // [0,1024) float4s
        int r = g >> 4, c4 = (g & 15) << 2;
        float4 v = make_float4(0.f, 0.f, 0.f, 0.f);
        int row = rowBase + r;
        if (row < N) v = *(const float4*)(hin + (size_t)row * 64 + c4);
        *(float4*)(&xs[r * 68 + c4]) = v;
    }
#pragma unroll
    for (int i = 0; i < 20; ++i) {
        int g = i * 256 + t;              // [0,5120)
        int k = g / 80, c = g % 80;
        wt[c * 68 + k] = W[g];
    }
    __syncthreads();
    const int tx = t & 15;   // cols 5tx..5tx+4
    const int ty = t >> 4;   // rows 4ty..4ty+3
    float acc[4][5] = {};
#pragma unroll
    for (int kc = 0; kc < 16; ++kc) {
        float4 a[4];
#pragma unroll
        for (int i = 0; i < 4; ++i) a[i] = *(const float4*)(&xs[(4 * ty + i) * 68 + kc * 4]);
        float4 w[5];
#pragma unroll
        for (int j = 0; j < 5; ++j) w[j] = *(const float4*)(&wt[(5 * tx + j) * 68 + kc * 4]);
#pragma unroll
        for (int i = 0; i < 4; ++i) {
#pragma unroll
            for (int j = 0; j < 5; ++j) {
                acc[i][j] += a[i].x * w[j].x + a[i].y * w[j].y + a[i].z * w[j].z + a[i].w * w[j].w;
            }
        }
    }
#pragma unroll
    for (int i = 0; i < 4; ++i) {
        int row = rowBase + 4 * ty + i;
        if (row < N) {
#pragma unroll
            for (int j = 0; j < 5; ++j) h2[(size_t)row * 80 + 5 * tx + j] = acc[i][j];
        }
    }
}

// ---------------- alpha projections ----------------
__global__ __launch_bounds__(256) void k_alpha1(const float* __restrict__ h1,
                                                const float* __restrict__ asrc,
                                                const float* __restrict__ adst,
                                                float* __restrict__ als, float* __restrict__ ald, int N) {
    int idx = blockIdx.x * 256 + threadIdx.x;
    if (idx >= N * 8) return;
    int n = idx >> 3, h = idx & 7;
    const float* p = h1 + (size_t)n * 64 + h * 8;
    float4 v0 = *(const float4*)p, v1 = *(const float4*)(p + 4);
    const float* a = asrc + h * 8;
    const float* d = adst + h * 8;
    float s = v0.x * a[0] + v0.y * a[1] + v0.z * a[2] + v0.w * a[3]
            + v1.x * a[4] + v1.y * a[5] + v1.z * a[6] + v1.w * a[7];
    float t = v0.x * d[0] + v0.y * d[1] + v0.z * d[2] + v0.w * d[3]
            + v1.x * d[4] + v1.y * d[5] + v1.z * d[6] + v1.w * d[7];
    als[idx] = s;
    ald[idx] = t;
}

__global__ __launch_bounds__(256) void k_alpha2(const float* __restrict__ h2,
                                                const float* __restrict__ asrc,
                                                const float* __restrict__ adst,
                                                float* __restrict__ als, float* __restrict__ ald, int N) {
    int idx = blockIdx.x * 256 + threadIdx.x;
    if (idx >= N * 8) return;
    int n = idx >> 3, h = idx & 7;
    const float* p = h2 + (size_t)n * 80 + h * 10;
    const float* a = asrc + h * 10;
    const float* d = adst + h * 10;
    float s = 0.f, t = 0.f;
#pragma unroll
    for (int c = 0; c < 10; ++c) {
        float v = p[c];
        s += v * a[c];
        t += v * d[c];
    }
    als[idx] = s;
    ald[idx] = t;
}

// ---------------- layer-1 aggregation: one wave per node ----------------
// lane = h*8+c. Softmax normalization deferred: acc/den at the end.
__global__ __launch_bounds__(256) void k_agg1(const int* __restrict__ cnt, const int* __restrict__ bucket,
                                              const float* __restrict__ h1,
                                              const float* __restrict__ als, const float* __restrict__ ald,
                                              const float* __restrict__ b1,
                                              float* __restrict__ helu, int N) {
    int wid = (blockIdx.x * blockDim.x + threadIdx.x) >> 6;
    int lane = threadIdx.x & 63;
    if (wid >= N) return;
    int n = wid, h = lane >> 3;
    float aldh = ald[(size_t)n * 8 + h];
    float wself = __expf(lrelu(als[(size_t)n * 8 + h] + aldh));
    float den = wself;
    float acc = wself * h1[(size_t)n * 64 + lane];
    int k = min(cnt[n], CAP);
    const int* bp = bucket + (size_t)n * CAP;
    auto P = [&](int s) {
        float w = __expf(lrelu(als[(size_t)s * 8 + h] + aldh));
        den += w;
        acc += w * h1[(size_t)s * 64 + lane];
    };
    int i = 0;
    for (; i + 4 <= k; i += 4) {
        int4 s4 = *(const int4*)(bp + i);
        P(s4.x); P(s4.y); P(s4.z); P(s4.w);
    }
    for (; i < k; ++i) P(bp[i]);
    float o = acc / den + b1[lane];
    helu[(size_t)n * 64 + lane] = o > 0.f ? o : __expf(o) - 1.f;
}

// ---------------- layer-2 aggregation + head-mean + log_softmax ----------------
// one wave per node, 80 outputs: lane handles o=lane, and o=64+lane for lane<16.
__global__ __launch_bounds__(256) void k_agg2(const int* __restrict__ cnt, const int* __restrict__ bucket,
                                              const float* __restrict__ h2,
                                              const float* __restrict__ als, const float* __restrict__ ald,
                                              const float* __restrict__ b2,
                                              float* __restrict__ out, int N) {
    __shared__ float sm[4][80];
    int w = threadIdx.x >> 6, lane = threadIdx.x & 63;
    int n = blockIdx.x * 4 + w;
    bool act = n < N;
    float m = 0.f;
    if (act) {
        int hA = lane / 10;               // 0..6
        int hB = (64 + lane) / 10;        // 6..7 (used when lane<16)
        float aldA = ald[(size_t)n * 8 + hA];
        float aldB = (lane < 16) ? ald[(size_t)n * 8 + hB] : 0.f;
        float wA = __expf(lrelu(als[(size_t)n * 8 + hA] + aldA));
        float denA = wA;
        float accA = wA * h2[(size_t)n * 80 + lane];
        float denB = 1.f, accB = 0.f;
        if (lane < 16) {
            float wB = __expf(lrelu(als[(size_t)n * 8 + hB] + aldB));
            denB = wB;
            accB = wB * h2[(size_t)n * 80 + 64 + lane];
        }
        int k = min(cnt[n], CAP);
        const int* bp = bucket + (size_t)n * CAP;
        auto P = [&](int s) {
            float wsA = __expf(lrelu(als[(size_t)s * 8 + hA] + aldA));
            denA += wsA;
            accA += wsA * h2[(size_t)s * 80 + lane];
            if (lane < 16) {
                float wsB = __expf(lrelu(als[(size_t)s * 8 + hB] + aldB));
                denB += wsB;
                accB += wsB * h2[(size_t)s * 80 + 64 + lane];
            }
        };
        int i = 0;
        for (; i + 4 <= k; i += 4) {
            int4 s4 = *(const int4*)(bp + i);
            P(s4.x); P(s4.y); P(s4.z); P(s4.w);
        }
        for (; i < k; ++i) P(bp[i]);
        sm[w][lane] = accA / denA;
        if (lane < 16) sm[w][64 + lane] = accB / denB;
    }
    __syncthreads();
    if (act && lane < 10) {
#pragma unroll
        for (int hh = 0; hh < 8; ++hh) m += sm[w][hh * 10 + lane];
        m = m * 0.125f + b2[lane];
    }
    __syncthreads();
    if (act && lane < 10) sm[w][lane] = m;
    __syncthreads();
    if (act && lane < 10) {
        float mx = -1e30f;
#pragma unroll
        for (int c = 0; c < 10; ++c) mx = fmaxf(mx, sm[w][c]);
        float ssum = 0.f;
#pragma unroll
        for (int c = 0; c < 10; ++c) ssum += __expf(sm[w][c] - mx);
        out[(size_t)n * 10 + lane] = m - mx - __logf(ssum);
    }
}

extern "C" void kernel_launch(void* const* d_in, const int* in_sizes, int n_in,
                              void* d_out, int out_size, void* d_ws, size_t ws_size,
                              hipStream_t stream) {
    const float* x     = (const float*)d_in[0];
    const int*   ei    = (const int*)d_in[1];
    const float* W1    = (const float*)d_in[2];
    const float* asrc1 = (const float*)d_in[3];
    const float* adst1 = (const float*)d_in[4];
    const float* b1    = (const float*)d_in[5];
    const float* W2    = (const float*)d_in[6];
    const float* asrc2 = (const float*)d_in[7];
    const float* adst2 = (const float*)d_in[8];
    const float* b2    = (const float*)d_in[9];
    float* out = (float*)d_out;

    int N = in_sizes[0] / 128;
    int E = in_sizes[1] / 2;

    char* base = (char*)d_ws;
    size_t off = 0;
    auto alloc = [&](size_t bytes) {
        char* p = base + off;
        off = (off + bytes + 255) & ~(size_t)255;
        return p;
    };
    int*   cnt    = (int*)alloc((size_t)N * 4);
    int*   bucket = (int*)alloc((size_t)N * CAP * 4);
    float* helu   = (float*)alloc((size_t)N * 64 * 4);
    char*  regA   = alloc((size_t)N * 96 * 4);   // h1+als1+ald1 (80N floats) / h2+als2+ald2 (96N floats)
    float* h1   = (float*)regA;
    float* als1 = (float*)(regA + (size_t)N * 64 * 4);
    float* ald1 = als1 + (size_t)N * 8;
    float* h2   = (float*)regA;                  // overwrites dead h1 after agg1
    float* als2 = (float*)(regA + (size_t)N * 80 * 4);
    float* ald2 = als2 + (size_t)N * 8;
    (void)ws_size; (void)n_in; (void)out_size;

    hipMemsetAsync(cnt, 0, (size_t)N * 4, stream);
    k_build<<<(E + 255) / 256, 256, 0, stream>>>(ei, E, cnt, bucket);
    k_gemm1<<<(N + 63) / 64, 256, 0, stream>>>(x, W1, h1, N);
    k_alpha1<<<(N * 8 + 255) / 256, 256, 0, stream>>>(h1, asrc1, adst1, als1, ald1, N);
    k_agg1<<<(N + 3) / 4, 256, 0, stream>>>(cnt, bucket, h1, als1, ald1, b1, helu, N);
    k_gemm2<<<(N + 63) / 64, 256, 0, stream>>>(helu, W2, h2, N);
    k_alpha2<<<(N * 8 + 255) / 256, 256, 0, stream>>>(h2, asrc2, adst2, als2, ald2, N);
    k_agg2<<<(N + 3) / 4, 256, 0, stream>>>(cnt, bucket, h2, als2, ald2, b2, out, N);
}

// Round 2
// 559.018 us; speedup vs baseline: 2.2419x; 2.2419x over previous
//
#include <hip/hip_runtime.h>
#include <hip/hip_bf16.h>
#include <cstdint>

#define CAP 64

__device__ __forceinline__ float lrelu(float v) { return fmaxf(v, 0.2f * v); }

// ---------------- CSR bucket build: one int atomic per edge ----------------
__global__ __launch_bounds__(256) void k_build(const int* __restrict__ ei, int E,
                                               int* __restrict__ cnt, int* __restrict__ bucket) {
    int e = blockIdx.x * 256 + threadIdx.x;
    if (e >= E) return;
    int s = ei[e];
    int d = ei[E + e];
    int slot = atomicAdd(&cnt[d], 1);
    if (slot < CAP) bucket[(size_t)d * CAP + slot] = s;
}

// ---------------- GEMM1: h1[N,64] = x[N,128] @ W1[128,64] ----------------
// x-tile AND W1 staged in LDS (no global loads in inner loop -> no spill).
__global__ __launch_bounds__(256) void k_gemm1(const float* __restrict__ x,
                                               const float* __restrict__ W,
                                               float* __restrict__ h1, int N) {
    __shared__ float xs[64 * 132];   // 33,792 B (pad 132 keeps b128 reads 2-way max)
    __shared__ float ws[128 * 64];   // 32,768 B
    const int t = threadIdx.x;
    const int rowBase = blockIdx.x * 64;
#pragma unroll
    for (int i = 0; i < 8; ++i) {
        int g = i * 256 + t;              // [0,2048) float4s of x-tile
        int r = g >> 5, c4 = (g & 31) << 2;
        float4 v = make_float4(0.f, 0.f, 0.f, 0.f);
        int row = rowBase + r;
        if (row < N) v = *(const float4*)(x + (size_t)row * 128 + c4);
        *(float4*)(&xs[r * 132 + c4]) = v;
    }
#pragma unroll
    for (int i = 0; i < 8; ++i) {
        int g = i * 256 + t;              // [0,2048) float4s of W
        *(float4*)(&ws[g * 4]) = *(const float4*)(W + (size_t)g * 4);
    }
    __syncthreads();
    const int tx = t & 15;   // cols 4tx..4tx+3
    const int ty = t >> 4;   // rows 4ty..4ty+3
    float acc[4][4] = {};
#pragma unroll 8
    for (int kc = 0; kc < 32; ++kc) {
        float4 a[4];
#pragma unroll
        for (int i = 0; i < 4; ++i) a[i] = *(const float4*)(&xs[(4 * ty + i) * 132 + kc * 4]);
        float4 w[4];
#pragma unroll
        for (int kk = 0; kk < 4; ++kk) w[kk] = *(const float4*)(&ws[(size_t)(kc * 4 + kk) * 64 + tx * 4]);
#pragma unroll
        for (int i = 0; i < 4; ++i) {
            const float* ai = (const float*)&a[i];
#pragma unroll
            for (int j = 0; j < 4; ++j) {
                acc[i][j] += ai[0] * ((const float*)&w[0])[j]
                           + ai[1] * ((const float*)&w[1])[j]
                           + ai[2] * ((const float*)&w[2])[j]
                           + ai[3] * ((const float*)&w[3])[j];
            }
        }
    }
#pragma unroll
    for (int i = 0; i < 4; ++i) {
        int row = rowBase + 4 * ty + i;
        if (row < N) {
            float4 o = make_float4(acc[i][0], acc[i][1], acc[i][2], acc[i][3]);
            *(float4*)(h1 + (size_t)row * 64 + tx * 4) = o;
        }
    }
}

// ---------------- GEMM2: h2[N,80] = helu[N,64] @ W2[64,80] ----------------
__global__ __launch_bounds__(256) void k_gemm2(const float* __restrict__ hin,
                                               const float* __restrict__ W,
                                               float* __restrict__ h2, int N) {
    __shared__ float xs[64 * 68];   // 17,408 B
    __shared__ float wt[80 * 68];   // 21,760 B (W2 transposed)
    const int t = threadIdx.x;
    const int rowBase = blockIdx.x * 64;
#pragma unroll
    for (int i = 0; i < 4; ++i) {
        int g = i * 256 + t;              // [0,1024) float4s
        int r = g >> 4, c4 = (g & 15) << 2;
        float4 v = make_float4(0.f, 0.f, 0.f, 0.f);
        int row = rowBase + r;
        if (row < N) v = *(const float4*)(hin + (size_t)row * 64 + c4);
        *(float4*)(&xs[r * 68 + c4]) = v;
    }
#pragma unroll
    for (int i = 0; i < 20; ++i) {
        int g = i * 256 + t;              // [0,5120)
        int k = g / 80, c = g % 80;
        wt[c * 68 + k] = W[g];
    }
    __syncthreads();
    const int tx = t & 15;   // cols 5tx..5tx+4
    const int ty = t >> 4;   // rows 4ty..4ty+3
    float acc[4][5] = {};
#pragma unroll 4
    for (int kc = 0; kc < 16; ++kc) {
        float4 a[4];
#pragma unroll
        for (int i = 0; i < 4; ++i) a[i] = *(const float4*)(&xs[(4 * ty + i) * 68 + kc * 4]);
        float4 w[5];
#pragma unroll
        for (int j = 0; j < 5; ++j) w[j] = *(const float4*)(&wt[(5 * tx + j) * 68 + kc * 4]);
#pragma unroll
        for (int i = 0; i < 4; ++i) {
#pragma unroll
            for (int j = 0; j < 5; ++j) {
                acc[i][j] += a[i].x * w[j].x + a[i].y * w[j].y + a[i].z * w[j].z + a[i].w * w[j].w;
            }
        }
    }
#pragma unroll
    for (int i = 0; i < 4; ++i) {
        int row = rowBase + 4 * ty + i;
        if (row < N) {
#pragma unroll
            for (int j = 0; j < 5; ++j) h2[(size_t)row * 80 + 5 * tx + j] = acc[i][j];
        }
    }
}

// ---------------- alpha projections ----------------
__global__ __launch_bounds__(256) void k_alpha1(const float* __restrict__ h1,
                                                const float* __restrict__ asrc,
                                                const float* __restrict__ adst,
                                                float* __restrict__ als, float* __restrict__ ald, int N) {
    int idx = blockIdx.x * 256 + threadIdx.x;
    if (idx >= N * 8) return;
    int n = idx >> 3, h = idx & 7;
    const float* p = h1 + (size_t)n * 64 + h * 8;
    float4 v0 = *(const float4*)p, v1 = *(const float4*)(p + 4);
    const float* a = asrc + h * 8;
    const float* d = adst + h * 8;
    float s = v0.x * a[0] + v0.y * a[1] + v0.z * a[2] + v0.w * a[3]
            + v1.x * a[4] + v1.y * a[5] + v1.z * a[6] + v1.w * a[7];
    float t = v0.x * d[0] + v0.y * d[1] + v0.z * d[2] + v0.w * d[3]
            + v1.x * d[4] + v1.y * d[5] + v1.z * d[6] + v1.w * d[7];
    als[idx] = s;
    ald[idx] = t;
}

__global__ __launch_bounds__(256) void k_alpha2(const float* __restrict__ h2,
                                                const float* __restrict__ asrc,
                                                const float* __restrict__ adst,
                                                float* __restrict__ als, float* __restrict__ ald, int N) {
    int idx = blockIdx.x * 256 + threadIdx.x;
    if (idx >= N * 8) return;
    int n = idx >> 3, h = idx & 7;
    const float* p = h2 + (size_t)n * 80 + h * 10;
    const float* a = asrc + h * 10;
    const float* d = adst + h * 10;
    float s = 0.f, t = 0.f;
#pragma unroll
    for (int c = 0; c < 10; ++c) {
        float v = p[c];
        s += v * a[c];
        t += v * d[c];
    }
    als[idx] = s;
    ald[idx] = t;
}

// ---------------- layer-1 aggregation: one wave per node ----------------
__global__ __launch_bounds__(256) void k_agg1(const int* __restrict__ cnt, const int* __restrict__ bucket,
                                              const float* __restrict__ h1,
                                              const float* __restrict__ als, const float* __restrict__ ald,
                                              const float* __restrict__ b1,
                                              float* __restrict__ helu, int N) {
    int wid = (blockIdx.x * blockDim.x + threadIdx.x) >> 6;
    int lane = threadIdx.x & 63;
    if (wid >= N) return;
    int n = wid, h = lane >> 3;
    float aldh = ald[(size_t)n * 8 + h];
    float wself = __expf(lrelu(als[(size_t)n * 8 + h] + aldh));
    float den = wself;
    float acc = wself * h1[(size_t)n * 64 + lane];
    int k = min(cnt[n], CAP);
    const int* bp = bucket + (size_t)n * CAP;
    auto P = [&](int s) {
        float w = __expf(lrelu(als[(size_t)s * 8 + h] + aldh));
        den += w;
        acc += w * h1[(size_t)s * 64 + lane];
    };
    int i = 0;
    for (; i + 4 <= k; i += 4) {
        int4 s4 = *(const int4*)(bp + i);
        P(s4.x); P(s4.y); P(s4.z); P(s4.w);
    }
    for (; i < k; ++i) P(bp[i]);
    float o = acc / den + b1[lane];
    helu[(size_t)n * 64 + lane] = o > 0.f ? o : __expf(o) - 1.f;
}

// ---------------- layer-2 aggregation + head-mean + log_softmax ----------------
__global__ __launch_bounds__(256) void k_agg2(const int* __restrict__ cnt, const int* __restrict__ bucket,
                                              const float* __restrict__ h2,
                                              const float* __restrict__ als, const float* __restrict__ ald,
                                              const float* __restrict__ b2,
                                              float* __restrict__ out, int N) {
    __shared__ float sm[4][80];
    int w = threadIdx.x >> 6, lane = threadIdx.x & 63;
    int n = blockIdx.x * 4 + w;
    bool act = n < N;
    float m = 0.f;
    if (act) {
        int hA = lane / 10;               // 0..6
        int hB = (64 + lane) / 10;        // 6..7 (used when lane<16)
        float aldA = ald[(size_t)n * 8 + hA];
        float aldB = (lane < 16) ? ald[(size_t)n * 8 + hB] : 0.f;
        float wA = __expf(lrelu(als[(size_t)n * 8 + hA] + aldA));
        float denA = wA;
        float accA = wA * h2[(size_t)n * 80 + lane];
        float denB = 1.f, accB = 0.f;
        if (lane < 16) {
            float wB = __expf(lrelu(als[(size_t)n * 8 + hB] + aldB));
            denB = wB;
            accB = wB * h2[(size_t)n * 80 + 64 + lane];
        }
        int k = min(cnt[n], CAP);
        const int* bp = bucket + (size_t)n * CAP;
        auto P = [&](int s) {
            float wsA = __expf(lrelu(als[(size_t)s * 8 + hA] + aldA));
            denA += wsA;
            accA += wsA * h2[(size_t)s * 80 + lane];
            if (lane < 16) {
                float wsB = __expf(lrelu(als[(size_t)s * 8 + hB] + aldB));
                denB += wsB;
                accB += wsB * h2[(size_t)s * 80 + 64 + lane];
            }
        };
        int i = 0;
        for (; i + 4 <= k; i += 4) {
            int4 s4 = *(const int4*)(bp + i);
            P(s4.x); P(s4.y); P(s4.z); P(s4.w);
        }
        for (; i < k; ++i) P(bp[i]);
        sm[w][lane] = accA / denA;
        if (lane < 16) sm[w][64 + lane] = accB / denB;
    }
    __syncthreads();
    if (act && lane < 10) {
#pragma unroll
        for (int hh = 0; hh < 8; ++hh) m += sm[w][hh * 10 + lane];
        m = m * 0.125f + b2[lane];
    }
    __syncthreads();
    if (act && lane < 10) sm[w][lane] = m;
    __syncthreads();
    if (act && lane < 10) {
        float mx = -1e30f;
#pragma unroll
        for (int c = 0; c < 10; ++c) mx = fmaxf(mx, sm[w][c]);
        float ssum = 0.f;
#pragma unroll
        for (int c = 0; c < 10; ++c) ssum += __expf(sm[w][c] - mx);
        out[(size_t)n * 10 + lane] = m - mx - __logf(ssum);
    }
}

extern "C" void kernel_launch(void* const* d_in, const int* in_sizes, int n_in,
                              void* d_out, int out_size, void* d_ws, size_t ws_size,
                              hipStream_t stream) {
    const float* x     = (const float*)d_in[0];
    const int*   ei    = (const int*)d_in[1];
    const float* W1    = (const float*)d_in[2];
    const float* asrc1 = (const float*)d_in[3];
    const float* adst1 = (const float*)d_in[4];
    const float* b1    = (const float*)d_in[5];
    const float* W2    = (const float*)d_in[6];
    const float* asrc2 = (const float*)d_in[7];
    const float* adst2 = (const float*)d_in[8];
    const float* b2    = (const float*)d_in[9];
    float* out = (float*)d_out;

    int N = in_sizes[0] / 128;
    int E = in_sizes[1] / 2;

    char* base = (char*)d_ws;
    size_t off = 0;
    auto alloc = [&](size_t bytes) {
        char* p = base + off;
        off = (off + bytes + 255) & ~(size_t)255;
        return p;
    };
    int*   cnt    = (int*)alloc((size_t)N * 4);
    int*   bucket = (int*)alloc((size_t)N * CAP * 4);
    float* helu   = (float*)alloc((size_t)N * 64 * 4);
    char*  regA   = alloc((size_t)N * 96 * 4);   // h1+als1+ald1 (80N floats) / h2+als2+ald2 (96N floats)
    float* h1   = (float*)regA;
    float* als1 = (float*)(regA + (size_t)N * 64 * 4);
    float* ald1 = als1 + (size_t)N * 8;
    float* h2   = (float*)regA;                  // overwrites dead h1 after agg1
    float* als2 = (float*)(regA + (size_t)N * 80 * 4);
    float* ald2 = als2 + (size_t)N * 8;
    (void)ws_size; (void)n_in; (void)out_size;

    hipMemsetAsync(cnt, 0, (size_t)N * 4, stream);
    k_build<<<(E + 255) / 256, 256, 0, stream>>>(ei, E, cnt, bucket);
    k_gemm1<<<(N + 63) / 64, 256, 0, stream>>>(x, W1, h1, N);
    k_alpha1<<<(N * 8 + 255) / 256, 256, 0, stream>>>(h1, asrc1, adst1, als1, ald1, N);
    k_agg1<<<(N + 3) / 4, 256, 0, stream>>>(cnt, bucket, h1, als1, ald1, b1, helu, N);
    k_gemm2<<<(N + 63) / 64, 256, 0, stream>>>(helu, W2, h2, N);
    k_alpha2<<<(N * 8 + 255) / 256, 256, 0, stream>>>(h2, asrc2, adst2, als2, ald2, N);
    k_agg2<<<(N + 3) / 4, 256, 0, stream>>>(cnt, bucket, h2, als2, ald2, b2, out, N);
}